// Round 3
// baseline (14647.618 us; speedup 1.0000x reference)
//
#include <hip/hip_runtime.h>
#include <hip/hip_bf16.h>

// ---------------------------------------------------------------------------
// LSTMTagger: char-LSTM (4096x16, H=128) -> word-LSTM (serial 4096, H=512)
//             -> linear(64) + log_softmax.
// Wire dtype of float tensors detected at runtime (bf16 vs f32); kernels
// dual-path on device flag ws[0]: 1 = bf16, 0 = f32.
//
// Word LSTM (round 7): fully wave-decoupled agents.
//   R2's sc0/single-XCD fast path FAILED (stale-L2 reads when placement
//   assumptions break; handshake can pass while steady-state polls go stale).
//   Abandoned -- back to the proven agent-scope protocol, now restructured:
//   64 WGs x 256 threads = 256 independent WAVES, each owning 2 h-slots.
//   - No __syncthreads in the loop, no hout relay: lanes 0/32 of each wave
//     store their slots' h directly (write-once + 0xFFFFFFFF sentinel makes
//     any store order safe). Store issues 200-400ns earlier; no 16-wave
//     convoy per WG.
//   - 1 wave per SIMD (4 waves/CU over 64 CUs): the 64-FMA dot no longer
//     4-way issue-serializes against sibling waves.
//   - dot uses 4 independent accumulators; xp2 prefetched 1 step ahead
//     (raw ushort, converted at use) so HBM latency hides under the poll.
// ---------------------------------------------------------------------------

#define OFF_FLAG  0
#define OFF_CEMB  16
#define OFF_CWIH  8208
#define OFF_CBIH  40976
#define OFF_CBHH  41488
#define OFF_CWHH  42000
#define OFF_BIH   107536
#define OFF_BHH   109584
#define OFF_W1T   111632
#define OFF_CGE   144400
#define OFF_CH    209936
#define OFF_XP2   734224
#define OFF_HH    4928528

#define SENT 0xFFFFFFFFu

__device__ __forceinline__ float sigf(float x) { return 1.0f / (1.0f + __expf(-x)); }
__device__ __forceinline__ float tanh_f(float x) { return 2.0f * sigf(2.0f * x) - 1.0f; }
__device__ __forceinline__ float b2f_lo(unsigned u) { return __uint_as_float(u << 16); }
__device__ __forceinline__ float b2f_hi(unsigned u) { return __uint_as_float(u & 0xFFFF0000u); }
__device__ __forceinline__ float4 dec2(uint2 u) {
    return make_float4(b2f_lo(u.x), b2f_hi(u.x), b2f_lo(u.y), b2f_hi(u.y));
}

// ---- D0: dtype detect. ---------------------------------------------------
__global__ void detect_kernel(const unsigned* __restrict__ w, int* __restrict__ flagp) {
    unsigned v = w[threadIdx.x];
    unsigned e = (v >> 7) & 0xFF;
    int inr = (e >= 100 && e <= 140) ? 1 : 0;
    unsigned long long m = __ballot(inr);
    if (threadIdx.x == 0) flagp[0] = (__popcll(m) >= 56) ? 1 : 0;
}

// ---- K0: (bf16|f32) -> f32 convert ---------------------------------------
__global__ void convf_kernel(const void* __restrict__ s, float* __restrict__ d,
                             int n, const int* __restrict__ flagp) {
    int i = blockIdx.x * 256 + threadIdx.x;
    if (i >= n) return;
    d[i] = flagp[0] ? __bfloat162float(((const __hip_bfloat16*)s)[i])
                    : ((const float*)s)[i];
}

// ---- K0b: W1 (64x512) -> W1T (512x64) f32 --------------------------------
__global__ void w1t_kernel(const void* __restrict__ W1, float* __restrict__ W1T,
                           const int* __restrict__ flagp) {
    int i = blockIdx.x * 256 + threadIdx.x;   // 0..32767
    int j = i & 63, k = i >> 6;
    W1T[i] = flagp[0] ? __bfloat162float(((const __hip_bfloat16*)W1)[j * 512 + k])
                      : ((const float*)W1)[j * 512 + k];
}

// ---- K1: char gate table ------------------------------------------------
__global__ void __launch_bounds__(256) cge_kernel(
    const float* __restrict__ cemb, const float* __restrict__ cWih,
    const float* __restrict__ cbih, const float* __restrict__ cbhh,
    float* __restrict__ cge)
{
    __shared__ float xe[64];
    int c = blockIdx.x, tid = threadIdx.x;
    if (tid < 64) xe[tid] = cemb[c * 64 + tid];
    __syncthreads();
#pragma unroll
    for (int rep = 0; rep < 2; ++rep) {
        int j = rep * 256 + tid;
        float acc = cbih[j] + cbhh[j];
#pragma unroll 8
        for (int k = 0; k < 64; ++k)
            acc += xe[k] * cWih[j * 64 + k];
        cge[c * 512 + j] = acc;
    }
}

// ---- K2: char LSTM -------------------------------------------------------
__global__ void __launch_bounds__(256) char_lstm_kernel(
    const float* __restrict__ cge, const float* __restrict__ Whh,
    const int* __restrict__ chars, const int* __restrict__ lens,
    float* __restrict__ char_h)
{
    __shared__ float hls[16][128];
    int tid = threadIdx.x;
    int wl = tid >> 4, sl = tid & 15;
    int w = blockIdx.x * 16 + wl;
    int len = lens[w];
    const int* cw = chars + w * 16;
    float c[8];
#pragma unroll
    for (int q = 0; q < 8; ++q) { c[q] = 0.0f; hls[wl][sl * 8 + q] = 0.0f; }

    for (int t = 0; t < 16; ++t) {
        __syncthreads();
        int ch = cw[t];
        const float* xg = cge + ch * 512;
        float acc[4][8];
#pragma unroll
        for (int g = 0; g < 4; ++g)
#pragma unroll
            for (int q = 0; q < 8; ++q)
                acc[g][q] = xg[g * 128 + sl * 8 + q];

        const float4* h4 = (const float4*)hls[wl];
#pragma unroll
        for (int g = 0; g < 4; ++g) {
            const float4* wbase = ((const float4*)Whh) + (g * 128 + sl * 8) * 32;
            for (int k4 = 0; k4 < 32; ++k4) {
                float4 hv = h4[k4];
#pragma unroll
                for (int q = 0; q < 8; ++q) {
                    float4 wv = wbase[q * 32 + k4];
                    acc[g][q] += wv.x * hv.x + wv.y * hv.y + wv.z * hv.z + wv.w * hv.w;
                }
            }
        }
        __syncthreads();
        if (t < len) {
#pragma unroll
            for (int q = 0; q < 8; ++q) {
                float iv = sigf(acc[0][q]);
                float fv = sigf(acc[1][q]);
                float gv = tanh_f(acc[2][q]);
                float ov = sigf(acc[3][q]);
                c[q] = fv * c[q] + iv * gv;
                hls[wl][sl * 8 + q] = ov * tanh_f(c[q]);
            }
        }
    }
    __syncthreads();
#pragma unroll
    for (int q = 0; q < 8; ++q)
        char_h[w * 128 + sl * 8 + q] = hls[wl][sl * 8 + q];
}

// ---- K3: word x-part gates (bf16 out) ------------------------------------
__global__ void __launch_bounds__(256) xp2_kernel(
    const void* __restrict__ wemb, const int* __restrict__ x,
    const float* __restrict__ char_h, const void* __restrict__ Wraw,
    const float* __restrict__ bih, const float* __restrict__ bhh,
    __hip_bfloat16* __restrict__ xp2, const int* __restrict__ flagp)
{
    __shared__ float feat[16][384];
    int flag = flagp[0];
    int tid = threadIdx.x, tl = tid >> 4, sl = tid & 15;
    int t = blockIdx.x * 16 + tl;
    int xw = x[t];
    for (int idx = sl; idx < 384; idx += 16) {
        float v;
        if (idx < 256)
            v = flag ? __bfloat162float(((const __hip_bfloat16*)wemb)[(size_t)xw * 256 + idx])
                     : ((const float*)wemb)[(size_t)xw * 256 + idx];
        else
            v = char_h[t * 128 + (idx - 256)];
        feat[tl][idx] = v;
    }
    __syncthreads();

    const float4* f4 = (const float4*)feat[tl];
    for (int rb = 0; rb < 4; ++rb) {
        int r0 = rb * 512 + sl * 32;
        for (int qc = 0; qc < 4; ++qc) {
            int rr = r0 + qc * 8;
            float acc[8];
#pragma unroll
            for (int q = 0; q < 8; ++q)
                acc[q] = bih[rr + q] + bhh[rr + q];
            if (!flag) {
                const float4* wb = ((const float4*)Wraw) + (size_t)rr * 96;
                for (int k4 = 0; k4 < 96; ++k4) {
                    float4 fv = f4[k4];
#pragma unroll
                    for (int q = 0; q < 8; ++q) {
                        float4 wv = wb[q * 96 + k4];
                        acc[q] += wv.x * fv.x + wv.y * fv.y + wv.z * fv.z + wv.w * fv.w;
                    }
                }
            } else {
                const uint2* wb = ((const uint2*)Wraw) + (size_t)rr * 96;
                for (int k4 = 0; k4 < 96; ++k4) {
                    float4 fv = f4[k4];
#pragma unroll
                    for (int q = 0; q < 8; ++q) {
                        uint2 wv = wb[q * 96 + k4];
                        acc[q] += b2f_lo(wv.x) * fv.x + b2f_hi(wv.x) * fv.y
                                + b2f_lo(wv.y) * fv.z + b2f_hi(wv.y) * fv.w;
                    }
                }
            }
#pragma unroll
            for (int q = 0; q < 8; ++q)
                xp2[(size_t)t * 2048 + rr + q] = __float2bfloat16(acc[q]);
        }
    }
}

// ---- K5: serial word LSTM (256 decoupled waves, 64 WGs x 4 waves) --------
__global__ void __launch_bounds__(256, 1) word_lstm_kernel(
    const __hip_bfloat16* __restrict__ xp2, const void* __restrict__ Whh_raw,
    float* __restrict__ h_hist, const int* __restrict__ flagp)
{
    __shared__ float hbuf[4][576];   // per-wave private staging, 16 chunks x (32+4 pad)
    int flag = flagp[0];
    int tid = threadIdx.x;
    int wave = tid >> 6, lane = tid & 63;
    int wgid = blockIdx.x * 4 + wave;   // global wave id, 0..255
    int sp = lane >> 5;                 // sub-slot 0/1 within the wave
    int g  = (lane >> 3) & 3;           // gate i/f/g/o
    int kk = lane & 7;                  // k-chunk (64 wide)
    int slot = wgid * 2 + sp;           // h-slot 0..511
    int grow = g * 512 + slot;          // gate row 0..2047

    // weights: Whh[grow][kk*64 .. +63] -> 16 NAMED float4 regs
    float4 w00, w01, w02, w03, w04, w05, w06, w07;
    float4 w08, w09, w10, w11, w12, w13, w14, w15;
    if (!flag) {
        const float4* wr = (const float4*)((const float*)Whh_raw + (size_t)grow * 512 + kk * 64);
        w00 = wr[0];  w01 = wr[1];  w02 = wr[2];  w03 = wr[3];
        w04 = wr[4];  w05 = wr[5];  w06 = wr[6];  w07 = wr[7];
        w08 = wr[8];  w09 = wr[9];  w10 = wr[10]; w11 = wr[11];
        w12 = wr[12]; w13 = wr[13]; w14 = wr[14]; w15 = wr[15];
    } else {
        const uint2* wr = (const uint2*)((const unsigned short*)Whh_raw + (size_t)grow * 512 + kk * 64);
        w00 = dec2(wr[0]);  w01 = dec2(wr[1]);  w02 = dec2(wr[2]);  w03 = dec2(wr[3]);
        w04 = dec2(wr[4]);  w05 = dec2(wr[5]);  w06 = dec2(wr[6]);  w07 = dec2(wr[7]);
        w08 = dec2(wr[8]);  w09 = dec2(wr[9]);  w10 = dec2(wr[10]); w11 = dec2(wr[11]);
        w12 = dec2(wr[12]); w13 = dec2(wr[13]); w14 = dec2(wr[14]); w15 = dec2(wr[15]);
    }

    unsigned* hview = (unsigned*)h_hist;
    const unsigned short* xpr = (const unsigned short*)xp2;
    float* wbuf = hbuf[wave];
    float c = 0.0f;
    int dead = 0;                       // sticky anti-hang

    // prefetch step-0 x gate (raw bf16; converted at use)
    unsigned short xraw = xpr[grow];

    for (int t = 0; t < 4096; ++t) {
        // prefetch next step's x gate BEFORE the poll -> latency hides in spin
        unsigned short xraw_nx = (t < 4095) ? xpr[(size_t)(t + 1) * 2048 + grow] : (unsigned short)0;

        if (t == 0) {
            // h_{-1} = 0 (dword d = 64*i + lane -> chunk d>>5, stride 36)
#pragma unroll
            for (int i = 0; i < 8; ++i)
                wbuf[(2 * i + (lane >> 5)) * 36 + (lane & 31)] = 0.0f;
        } else {
            // poll h_{t-1}: lane l loads dwords l + 64i (coalesced 256B per instr)
            const unsigned* src = hview + (size_t)(t - 1) * 512 + lane;
            unsigned v[8];
            unsigned spins = 0;
            for (;;) {
#pragma unroll
                for (int i = 0; i < 8; ++i)
                    v[i] = __hip_atomic_load(src + (size_t)i * 64, __ATOMIC_RELAXED,
                                             __HIP_MEMORY_SCOPE_AGENT);
                int ok = 1;
#pragma unroll
                for (int i = 0; i < 8; ++i) ok &= (v[i] != SENT);
                if (dead || __all(ok)) break;
                if (++spins > (1u << 22)) { dead = 1; break; }
            }
            if (dead) {
#pragma unroll
                for (int i = 0; i < 8; ++i)
                    if (v[i] == SENT) v[i] = __float_as_uint(12345.0f);
            }
            // wave-private LDS stage; same-wave ordering, no barrier needed
#pragma unroll
            for (int i = 0; i < 8; ++i)
                wbuf[(2 * i + (lane >> 5)) * 36 + (lane & 31)] = __uint_as_float(v[i]);
        }

        // dot: h[kk*64 .. +63] . w, 4 independent accumulator chains
        const float4* p0 = (const float4*)(wbuf + kk * 72);
        const float4* p1 = (const float4*)(wbuf + kk * 72 + 36);
        float a0 = 0.0f, a1 = 0.0f, a2 = 0.0f, a3 = 0.0f;
        {
            float4 hv;
#define FMA4_(A, W, HV) A += (W).x*(HV).x + (W).y*(HV).y + (W).z*(HV).z + (W).w*(HV).w
            hv = p0[0]; FMA4_(a0, w00, hv);  hv = p0[1]; FMA4_(a1, w01, hv);
            hv = p0[2]; FMA4_(a2, w02, hv);  hv = p0[3]; FMA4_(a3, w03, hv);
            hv = p0[4]; FMA4_(a0, w04, hv);  hv = p0[5]; FMA4_(a1, w05, hv);
            hv = p0[6]; FMA4_(a2, w06, hv);  hv = p0[7]; FMA4_(a3, w07, hv);
            hv = p1[0]; FMA4_(a0, w08, hv);  hv = p1[1]; FMA4_(a1, w09, hv);
            hv = p1[2]; FMA4_(a2, w10, hv);  hv = p1[3]; FMA4_(a3, w11, hv);
            hv = p1[4]; FMA4_(a0, w12, hv);  hv = p1[5]; FMA4_(a1, w13, hv);
            hv = p1[6]; FMA4_(a2, w14, hv);  hv = p1[7]; FMA4_(a3, w15, hv);
#undef FMA4_
        }
        float acc = (a0 + a1) + (a2 + a3);
        acc += __shfl_xor(acc, 1);
        acc += __shfl_xor(acc, 2);
        acc += __shfl_xor(acc, 4);
        float gvt = acc + __bfloat162float(*(const __hip_bfloat16*)&xraw);

        float iv = __shfl(gvt, sp * 32 + 0);
        float fv = __shfl(gvt, sp * 32 + 8);
        float gg = __shfl(gvt, sp * 32 + 16);
        float ov = __shfl(gvt, sp * 32 + 24);
        c = sigf(fv) * c + sigf(iv) * tanh_f(gg);
        float h = sigf(ov) * tanh_f(c);

        // direct per-wave store: lanes 0/32 publish this wave's 2 slots.
        // write-once + sentinel => any order safe; no relay, no barrier.
        if ((lane & 31) == 0)
            __hip_atomic_store(hview + (size_t)t * 512 + slot,
                               __float_as_uint(h),
                               __ATOMIC_RELAXED, __HIP_MEMORY_SCOPE_AGENT);

        xraw = xraw_nx;
    }
}

// ---- K6: logits + log_softmax --------------------------------------------
__global__ void __launch_bounds__(64) out_kernel(
    const float* __restrict__ h_hist, const float* __restrict__ W1T,
    const void* __restrict__ b1raw, void* __restrict__ out,
    const int* __restrict__ flagp)
{
    __shared__ float hb[512];
    int flag = flagp[0];
    int t = blockIdx.x, j = threadIdx.x;
    const float4* src = (const float4*)(h_hist + (size_t)t * 512);
    ((float4*)hb)[j * 2] = src[j * 2];
    ((float4*)hb)[j * 2 + 1] = src[j * 2 + 1];
    __syncthreads();

    float acc = flag ? __bfloat162float(((const __hip_bfloat16*)b1raw)[j])
                     : ((const float*)b1raw)[j];
#pragma unroll 8
    for (int k = 0; k < 512; ++k)
        acc += hb[k] * W1T[k * 64 + j];

    float m = acc;
#pragma unroll
    for (int o = 32; o; o >>= 1) m = fmaxf(m, __shfl_xor(m, o));
    float e = __expf(acc - m);
    float s = e;
#pragma unroll
    for (int o = 32; o; o >>= 1) s += __shfl_xor(s, o);
    float r = acc - m - __logf(s);
    if (flag) ((__hip_bfloat16*)out)[t * 64 + j] = __float2bfloat16(r);
    else      ((float*)out)[t * 64 + j] = r;
}

extern "C" void kernel_launch(void* const* d_in, const int* in_sizes, int n_in,
                              void* d_out, int out_size, void* d_ws, size_t ws_size,
                              hipStream_t stream)
{
    (void)in_sizes; (void)n_in; (void)out_size; (void)ws_size;
    const void* char_emb = d_in[0];
    const void* char_Wih = d_in[1];
    const void* char_Whh = d_in[2];
    const void* char_bih = d_in[3];
    const void* char_bhh = d_in[4];
    const void* word_emb = d_in[5];
    const void* Wih      = d_in[6];
    const void* Whh      = d_in[7];
    const void* bih      = d_in[8];
    const void* bhh      = d_in[9];
    const void* W1       = d_in[10];
    const void* b1       = d_in[11];
    const int* x     = (const int*)d_in[12];
    const int* chars = (const int*)d_in[13];
    const int* lens  = (const int*)d_in[14];

    float* ws    = (float*)d_ws;
    int*   flagp = (int*)(ws + OFF_FLAG);
    float* cembf = ws + OFF_CEMB;
    float* cWihf = ws + OFF_CWIH;
    float* cbihf = ws + OFF_CBIH;
    float* cbhhf = ws + OFF_CBHH;
    float* cWhhf = ws + OFF_CWHH;
    float* bihf  = ws + OFF_BIH;
    float* bhhf  = ws + OFF_BHH;
    float* W1T   = ws + OFF_W1T;
    float* cge   = ws + OFF_CGE;
    float* charh = ws + OFF_CH;
    __hip_bfloat16* xp2 = (__hip_bfloat16*)(ws + OFF_XP2);
    float* hh    = ws + OFF_HH;

    hipMemsetAsync(hh, 0xFF, (size_t)4096 * 512 * 4, stream);

    detect_kernel<<<1, 64, 0, stream>>>((const unsigned*)char_emb, flagp);

    convf_kernel<<<(8192 + 255) / 256, 256, 0, stream>>>(char_emb, cembf, 8192, flagp);
    convf_kernel<<<(32768 + 255) / 256, 256, 0, stream>>>(char_Wih, cWihf, 32768, flagp);
    convf_kernel<<<2, 256, 0, stream>>>(char_bih, cbihf, 512, flagp);
    convf_kernel<<<2, 256, 0, stream>>>(char_bhh, cbhhf, 512, flagp);
    convf_kernel<<<(65536 + 255) / 256, 256, 0, stream>>>(char_Whh, cWhhf, 65536, flagp);
    convf_kernel<<<8, 256, 0, stream>>>(bih, bihf, 2048, flagp);
    convf_kernel<<<8, 256, 0, stream>>>(bhh, bhhf, 2048, flagp);
    w1t_kernel<<<128, 256, 0, stream>>>(W1, W1T, flagp);

    cge_kernel<<<128, 256, 0, stream>>>(cembf, cWihf, cbihf, cbhhf, cge);
    char_lstm_kernel<<<256, 256, 0, stream>>>(cge, cWhhf, chars, lens, charh);
    xp2_kernel<<<256, 256, 0, stream>>>(word_emb, x, charh, Wih, bihf, bhhf, xp2, flagp);
    word_lstm_kernel<<<64, 256, 0, stream>>>(xp2, Whh, hh, flagp);
    out_kernel<<<4096, 64, 0, stream>>>(hh, W1T, b1, d_out, flagp);
}

// Round 4
// 13845.061 us; speedup vs baseline: 1.0580x; 1.0580x over previous
//
#include <hip/hip_runtime.h>
#include <hip/hip_bf16.h>

// ---------------------------------------------------------------------------
// LSTMTagger: char-LSTM (4096x16, H=128) -> word-LSTM (serial 4096, H=512)
//             -> linear(64) + log_softmax.
// Wire dtype of float tensors detected at runtime (bf16 vs f32); kernels
// dual-path on device flag ws[0]: 1 = bf16, 0 = f32.
//
// Word LSTM (round 8): R1 topology (16 WGs x 16 waves, hout relay + ONE
// coalesced line store per WG) -- R3's decoupled waves REGRESSED (WRITE_SIZE
// 4x from 8-writers-per-line; E[max of 256 decorrelated arrivals] > E[max of
// 16 synchronized]). New this round, attacking the fabric transaction itself:
//  - bf16 h payload: WG's 32 h = 64B = ONE line; row = 1KB = 16 lines;
//    poll is 4 loads/lane. Sentinel per dword still sound (valid bf16 pair
//    can never be 0xFFFFFFFF).
//  - own-line staged from double-buffered LDS hout[2][32] (f32, exact);
//    poll waits on the 15 REMOTE lines only -> the max-over-WGs cadence
//    loses its self-visibility term.
//  - weights pinned in regs via opaque asm (R1/R3 VGPR_Count=52 proves the
//    16 float4 weights were rematerialized as in-loop L2 loads).
// hout reuse safety: wave at step t+1 writes hout[(t+1)&1]; any same-WG wave
// still staging step t reads hout[(t-1)&1] -- different buffer; and a wave
// can be at most 1 step ahead (its poll needs all WGs' step-t stores, which
// needs own wave0 past the step-t barrier, which needs all own waves there).
// ---------------------------------------------------------------------------

#define OFF_FLAG  0
#define OFF_CEMB  16
#define OFF_CWIH  8208
#define OFF_CBIH  40976
#define OFF_CBHH  41488
#define OFF_CWHH  42000
#define OFF_BIH   107536
#define OFF_BHH   109584
#define OFF_W1T   111632
#define OFF_CGE   144400
#define OFF_CH    209936
#define OFF_XP2   734224
#define OFF_HH    4928528

#define SENT 0xFFFFFFFFu

__device__ __forceinline__ float sigf(float x) { return 1.0f / (1.0f + __expf(-x)); }
__device__ __forceinline__ float tanh_f(float x) { return 2.0f * sigf(2.0f * x) - 1.0f; }
__device__ __forceinline__ float b2f_lo(unsigned u) { return __uint_as_float(u << 16); }
__device__ __forceinline__ float b2f_hi(unsigned u) { return __uint_as_float(u & 0xFFFF0000u); }
__device__ __forceinline__ float4 dec2(uint2 u) {
    return make_float4(b2f_lo(u.x), b2f_hi(u.x), b2f_lo(u.y), b2f_hi(u.y));
}
__device__ __forceinline__ unsigned f2bf_bits(float f) {   // RNE f32 -> bf16 bits
    unsigned b = __float_as_uint(f);
    b += 0x7FFFu + ((b >> 16) & 1u);
    return b >> 16;
}

// ---- D0: dtype detect. ---------------------------------------------------
__global__ void detect_kernel(const unsigned* __restrict__ w, int* __restrict__ flagp) {
    unsigned v = w[threadIdx.x];
    unsigned e = (v >> 7) & 0xFF;
    int inr = (e >= 100 && e <= 140) ? 1 : 0;
    unsigned long long m = __ballot(inr);
    if (threadIdx.x == 0) flagp[0] = (__popcll(m) >= 56) ? 1 : 0;
}

// ---- K0: (bf16|f32) -> f32 convert ---------------------------------------
__global__ void convf_kernel(const void* __restrict__ s, float* __restrict__ d,
                             int n, const int* __restrict__ flagp) {
    int i = blockIdx.x * 256 + threadIdx.x;
    if (i >= n) return;
    d[i] = flagp[0] ? __bfloat162float(((const __hip_bfloat16*)s)[i])
                    : ((const float*)s)[i];
}

// ---- K0b: W1 (64x512) -> W1T (512x64) f32 --------------------------------
__global__ void w1t_kernel(const void* __restrict__ W1, float* __restrict__ W1T,
                           const int* __restrict__ flagp) {
    int i = blockIdx.x * 256 + threadIdx.x;   // 0..32767
    int j = i & 63, k = i >> 6;
    W1T[i] = flagp[0] ? __bfloat162float(((const __hip_bfloat16*)W1)[j * 512 + k])
                      : ((const float*)W1)[j * 512 + k];
}

// ---- K1: char gate table ------------------------------------------------
__global__ void __launch_bounds__(256) cge_kernel(
    const float* __restrict__ cemb, const float* __restrict__ cWih,
    const float* __restrict__ cbih, const float* __restrict__ cbhh,
    float* __restrict__ cge)
{
    __shared__ float xe[64];
    int c = blockIdx.x, tid = threadIdx.x;
    if (tid < 64) xe[tid] = cemb[c * 64 + tid];
    __syncthreads();
#pragma unroll
    for (int rep = 0; rep < 2; ++rep) {
        int j = rep * 256 + tid;
        float acc = cbih[j] + cbhh[j];
#pragma unroll 8
        for (int k = 0; k < 64; ++k)
            acc += xe[k] * cWih[j * 64 + k];
        cge[c * 512 + j] = acc;
    }
}

// ---- K2: char LSTM -------------------------------------------------------
__global__ void __launch_bounds__(256) char_lstm_kernel(
    const float* __restrict__ cge, const float* __restrict__ Whh,
    const int* __restrict__ chars, const int* __restrict__ lens,
    float* __restrict__ char_h)
{
    __shared__ float hls[16][128];
    int tid = threadIdx.x;
    int wl = tid >> 4, sl = tid & 15;
    int w = blockIdx.x * 16 + wl;
    int len = lens[w];
    const int* cw = chars + w * 16;
    float c[8];
#pragma unroll
    for (int q = 0; q < 8; ++q) { c[q] = 0.0f; hls[wl][sl * 8 + q] = 0.0f; }

    for (int t = 0; t < 16; ++t) {
        __syncthreads();
        int ch = cw[t];
        const float* xg = cge + ch * 512;
        float acc[4][8];
#pragma unroll
        for (int g = 0; g < 4; ++g)
#pragma unroll
            for (int q = 0; q < 8; ++q)
                acc[g][q] = xg[g * 128 + sl * 8 + q];

        const float4* h4 = (const float4*)hls[wl];
#pragma unroll
        for (int g = 0; g < 4; ++g) {
            const float4* wbase = ((const float4*)Whh) + (g * 128 + sl * 8) * 32;
            for (int k4 = 0; k4 < 32; ++k4) {
                float4 hv = h4[k4];
#pragma unroll
                for (int q = 0; q < 8; ++q) {
                    float4 wv = wbase[q * 32 + k4];
                    acc[g][q] += wv.x * hv.x + wv.y * hv.y + wv.z * hv.z + wv.w * hv.w;
                }
            }
        }
        __syncthreads();
        if (t < len) {
#pragma unroll
            for (int q = 0; q < 8; ++q) {
                float iv = sigf(acc[0][q]);
                float fv = sigf(acc[1][q]);
                float gv = tanh_f(acc[2][q]);
                float ov = sigf(acc[3][q]);
                c[q] = fv * c[q] + iv * gv;
                hls[wl][sl * 8 + q] = ov * tanh_f(c[q]);
            }
        }
    }
    __syncthreads();
#pragma unroll
    for (int q = 0; q < 8; ++q)
        char_h[w * 128 + sl * 8 + q] = hls[wl][sl * 8 + q];
}

// ---- K3: word x-part gates (bf16 out) ------------------------------------
__global__ void __launch_bounds__(256) xp2_kernel(
    const void* __restrict__ wemb, const int* __restrict__ x,
    const float* __restrict__ char_h, const void* __restrict__ Wraw,
    const float* __restrict__ bih, const float* __restrict__ bhh,
    __hip_bfloat16* __restrict__ xp2, const int* __restrict__ flagp)
{
    __shared__ float feat[16][384];
    int flag = flagp[0];
    int tid = threadIdx.x, tl = tid >> 4, sl = tid & 15;
    int t = blockIdx.x * 16 + tl;
    int xw = x[t];
    for (int idx = sl; idx < 384; idx += 16) {
        float v;
        if (idx < 256)
            v = flag ? __bfloat162float(((const __hip_bfloat16*)wemb)[(size_t)xw * 256 + idx])
                     : ((const float*)wemb)[(size_t)xw * 256 + idx];
        else
            v = char_h[t * 128 + (idx - 256)];
        feat[tl][idx] = v;
    }
    __syncthreads();

    const float4* f4 = (const float4*)feat[tl];
    for (int rb = 0; rb < 4; ++rb) {
        int r0 = rb * 512 + sl * 32;
        for (int qc = 0; qc < 4; ++qc) {
            int rr = r0 + qc * 8;
            float acc[8];
#pragma unroll
            for (int q = 0; q < 8; ++q)
                acc[q] = bih[rr + q] + bhh[rr + q];
            if (!flag) {
                const float4* wb = ((const float4*)Wraw) + (size_t)rr * 96;
                for (int k4 = 0; k4 < 96; ++k4) {
                    float4 fv = f4[k4];
#pragma unroll
                    for (int q = 0; q < 8; ++q) {
                        float4 wv = wb[q * 96 + k4];
                        acc[q] += wv.x * fv.x + wv.y * fv.y + wv.z * fv.z + wv.w * fv.w;
                    }
                }
            } else {
                const uint2* wb = ((const uint2*)Wraw) + (size_t)rr * 96;
                for (int k4 = 0; k4 < 96; ++k4) {
                    float4 fv = f4[k4];
#pragma unroll
                    for (int q = 0; q < 8; ++q) {
                        uint2 wv = wb[q * 96 + k4];
                        acc[q] += b2f_lo(wv.x) * fv.x + b2f_hi(wv.x) * fv.y
                                + b2f_lo(wv.y) * fv.z + b2f_hi(wv.y) * fv.w;
                    }
                }
            }
#pragma unroll
            for (int q = 0; q < 8; ++q)
                xp2[(size_t)t * 2048 + rr + q] = __float2bfloat16(acc[q]);
        }
    }
}

// ---- K5: serial word LSTM (16 WGs, bf16 line payload, remote-only poll) ---
__global__ void __launch_bounds__(1024, 4) word_lstm_kernel(
    const __hip_bfloat16* __restrict__ xp2, const void* __restrict__ Whh_raw,
    unsigned* __restrict__ hview, const int* __restrict__ flagp)
{
    __shared__ float hbuf[16][576];  // per-wave staging, 16 chunks x (32+4 pad)
    __shared__ float hout[2][32];    // double-buffered fresh h (f32)
    int flag = flagp[0];
    int wg = blockIdx.x;
    int tid = threadIdx.x;
    int wave = tid >> 6, lane = tid & 63;
    int sp = lane >> 5;              // sub-slot 0/1 within the wave
    int g  = (lane >> 3) & 3;        // gate i/f/g/o
    int kk = lane & 7;               // k-chunk (64 wide)
    int slot = wg * 32 + wave * 2 + sp;
    int grow = g * 512 + slot;
    // poll geometry: row = 256 dwords (512 bf16); lane covers dwords lane+64i.
    // own-WG dwords are [wg*16, wg*16+16): lane has one own dword iff
    // (lane>>4) == (wg&3), at i = wg>>2.
    int ownidx = ((lane >> 4) == (wg & 3)) ? (wg >> 2) : -1;

    // weights: Whh[grow][kk*64 .. +63] -> 16 float4, pinned via opaque asm
    float4 w00, w01, w02, w03, w04, w05, w06, w07;
    float4 w08, w09, w10, w11, w12, w13, w14, w15;
    if (!flag) {
        const float4* wr = (const float4*)((const float*)Whh_raw + (size_t)grow * 512 + kk * 64);
        w00 = wr[0];  w01 = wr[1];  w02 = wr[2];  w03 = wr[3];
        w04 = wr[4];  w05 = wr[5];  w06 = wr[6];  w07 = wr[7];
        w08 = wr[8];  w09 = wr[9];  w10 = wr[10]; w11 = wr[11];
        w12 = wr[12]; w13 = wr[13]; w14 = wr[14]; w15 = wr[15];
    } else {
        const uint2* wr = (const uint2*)((const unsigned short*)Whh_raw + (size_t)grow * 512 + kk * 64);
        w00 = dec2(wr[0]);  w01 = dec2(wr[1]);  w02 = dec2(wr[2]);  w03 = dec2(wr[3]);
        w04 = dec2(wr[4]);  w05 = dec2(wr[5]);  w06 = dec2(wr[6]);  w07 = dec2(wr[7]);
        w08 = dec2(wr[8]);  w09 = dec2(wr[9]);  w10 = dec2(wr[10]); w11 = dec2(wr[11]);
        w12 = dec2(wr[12]); w13 = dec2(wr[13]); w14 = dec2(wr[14]); w15 = dec2(wr[15]);
    }
    // pin: opaque defs prevent rematerialization-as-loads inside the loop
#define PIN4(a,b,c,d) asm volatile("" : "+v"(a.x),"+v"(a.y),"+v"(a.z),"+v"(a.w), \
    "+v"(b.x),"+v"(b.y),"+v"(b.z),"+v"(b.w), "+v"(c.x),"+v"(c.y),"+v"(c.z),"+v"(c.w), \
    "+v"(d.x),"+v"(d.y),"+v"(d.z),"+v"(d.w))
    PIN4(w00, w01, w02, w03); PIN4(w04, w05, w06, w07);
    PIN4(w08, w09, w10, w11); PIN4(w12, w13, w14, w15);
#undef PIN4

    const unsigned short* xpr = (const unsigned short*)xp2;
    float* wbuf = hbuf[wave];
    float c = 0.0f;
    int dead = 0;                    // sticky anti-hang

    for (int t = 0; t < 4096; ++t) {
        // h-independent: issue before the poll so latency hides under the spin
        unsigned short xraw = xpr[(size_t)t * 2048 + grow];

        if (t == 0) {
            // h_{-1} = 0 (value v -> chunk v>>5, offset v&31, stride 36)
#pragma unroll
            for (int i = 0; i < 8; ++i)
                wbuf[(2 * i + (lane >> 5)) * 36 + (lane & 31)] = 0.0f;
        } else {
            const unsigned* src = hview + (size_t)(t - 1) * 256;
            const float* houtprev = hout[(t - 1) & 1];
            unsigned v[4];
            unsigned spins = 0;
            for (;;) {
#pragma unroll
                for (int i = 0; i < 4; ++i)
                    v[i] = __hip_atomic_load(src + lane + i * 64, __ATOMIC_RELAXED,
                                             __HIP_MEMORY_SCOPE_AGENT);
                int ok = 1;
#pragma unroll
                for (int i = 0; i < 4; ++i) ok &= (i == ownidx) | (v[i] != SENT);
                if (dead || __all(ok)) break;
                if (++spins > (1u << 22)) { dead = 1; break; }
            }
            if (dead) {
#pragma unroll
                for (int i = 0; i < 4; ++i)
                    if (i != ownidx && v[i] == SENT) v[i] = 0x3f803f80u;  // 1.0,1.0
            }
            // stage: dword d = lane+64i -> values 2d,2d+1 -> chunk (lane>>4)+4i,
            // offset 2*(lane&15). Own dword comes from LDS hout (exact f32).
#pragma unroll
            for (int i = 0; i < 4; ++i) {
                int ch = (lane >> 4) + 4 * i;
                float f0, f1;
                if (i == ownidx) {
                    f0 = houtprev[2 * (lane & 15)];
                    f1 = houtprev[2 * (lane & 15) + 1];
                } else {
                    f0 = b2f_lo(v[i]);
                    f1 = b2f_hi(v[i]);
                }
                wbuf[ch * 36 + 2 * (lane & 15)]     = f0;
                wbuf[ch * 36 + 2 * (lane & 15) + 1] = f1;
            }
        }

        // dot: h[kk*64 .. +63] . w  (chunks 2kk, 2kk+1), 4 independent chains
        const float4* p0 = (const float4*)(wbuf + kk * 72);
        const float4* p1 = (const float4*)(wbuf + kk * 72 + 36);
        float a0 = 0.0f, a1 = 0.0f, a2 = 0.0f, a3 = 0.0f;
        {
            float4 hv;
#define FMA4_(A, W, HV) A += (W).x*(HV).x + (W).y*(HV).y + (W).z*(HV).z + (W).w*(HV).w
            hv = p0[0]; FMA4_(a0, w00, hv);  hv = p0[1]; FMA4_(a1, w01, hv);
            hv = p0[2]; FMA4_(a2, w02, hv);  hv = p0[3]; FMA4_(a3, w03, hv);
            hv = p0[4]; FMA4_(a0, w04, hv);  hv = p0[5]; FMA4_(a1, w05, hv);
            hv = p0[6]; FMA4_(a2, w06, hv);  hv = p0[7]; FMA4_(a3, w07, hv);
            hv = p1[0]; FMA4_(a0, w08, hv);  hv = p1[1]; FMA4_(a1, w09, hv);
            hv = p1[2]; FMA4_(a2, w10, hv);  hv = p1[3]; FMA4_(a3, w11, hv);
            hv = p1[4]; FMA4_(a0, w12, hv);  hv = p1[5]; FMA4_(a1, w13, hv);
            hv = p1[6]; FMA4_(a2, w14, hv);  hv = p1[7]; FMA4_(a3, w15, hv);
#undef FMA4_
        }
        float acc = (a0 + a1) + (a2 + a3);
        acc += __shfl_xor(acc, 1);
        acc += __shfl_xor(acc, 2);
        acc += __shfl_xor(acc, 4);
        float gvt = acc + __bfloat162float(*(const __hip_bfloat16*)&xraw);

        float iv = __shfl(gvt, sp * 32 + 0);
        float fv = __shfl(gvt, sp * 32 + 8);
        float gg = __shfl(gvt, sp * 32 + 16);
        float ov = __shfl(gvt, sp * 32 + 24);
        c = sigf(fv) * c + sigf(iv) * tanh_f(gg);
        float h = sigf(ov) * tanh_f(c);

        if ((lane & 31) == 0) hout[t & 1][wave * 2 + sp] = h;
        __syncthreads();                 // hout complete

        if (wave == 0 && lane < 16) {
            // pack 2 h -> bf16x2 dword; ONE 64B-line store for the whole WG
            unsigned u0 = f2bf_bits(hout[t & 1][2 * lane]);
            unsigned u1 = f2bf_bits(hout[t & 1][2 * lane + 1]);
            __hip_atomic_store(hview + (size_t)t * 256 + wg * 16 + lane,
                               u0 | (u1 << 16),
                               __ATOMIC_RELAXED, __HIP_MEMORY_SCOPE_AGENT);
        }
        // no trailing barrier: hout[t&1] is next written at step t+2 (other
        // buffer at t+1); any same-WG wave reaching t+2 implies all waves
        // passed the t+1 barrier, hence all t-reads of hout are done.
    }
}

// ---- K6: logits + log_softmax (h_hist is bf16) ---------------------------
__global__ void __launch_bounds__(64) out_kernel(
    const unsigned short* __restrict__ hh16, const float* __restrict__ W1T,
    const void* __restrict__ b1raw, void* __restrict__ out,
    const int* __restrict__ flagp)
{
    __shared__ float hb[512];
    int flag = flagp[0];
    int t = blockIdx.x, j = threadIdx.x;
    const unsigned* src = (const unsigned*)(hh16 + (size_t)t * 512);
#pragma unroll
    for (int kq = 0; kq < 4; ++kq) {
        unsigned u = src[j * 4 + kq];
        hb[j * 8 + 2 * kq]     = b2f_lo(u);
        hb[j * 8 + 2 * kq + 1] = b2f_hi(u);
    }
    __syncthreads();

    float acc = flag ? __bfloat162float(((const __hip_bfloat16*)b1raw)[j])
                     : ((const float*)b1raw)[j];
#pragma unroll 8
    for (int k = 0; k < 512; ++k)
        acc += hb[k] * W1T[k * 64 + j];

    float m = acc;
#pragma unroll
    for (int o = 32; o; o >>= 1) m = fmaxf(m, __shfl_xor(m, o));
    float e = __expf(acc - m);
    float s = e;
#pragma unroll
    for (int o = 32; o; o >>= 1) s += __shfl_xor(s, o);
    float r = acc - m - __logf(s);
    if (flag) ((__hip_bfloat16*)out)[t * 64 + j] = __float2bfloat16(r);
    else      ((float*)out)[t * 64 + j] = r;
}

extern "C" void kernel_launch(void* const* d_in, const int* in_sizes, int n_in,
                              void* d_out, int out_size, void* d_ws, size_t ws_size,
                              hipStream_t stream)
{
    (void)in_sizes; (void)n_in; (void)out_size; (void)ws_size;
    const void* char_emb = d_in[0];
    const void* char_Wih = d_in[1];
    const void* char_Whh = d_in[2];
    const void* char_bih = d_in[3];
    const void* char_bhh = d_in[4];
    const void* word_emb = d_in[5];
    const void* Wih      = d_in[6];
    const void* Whh      = d_in[7];
    const void* bih      = d_in[8];
    const void* bhh      = d_in[9];
    const void* W1       = d_in[10];
    const void* b1       = d_in[11];
    const int* x     = (const int*)d_in[12];
    const int* chars = (const int*)d_in[13];
    const int* lens  = (const int*)d_in[14];

    float* ws    = (float*)d_ws;
    int*   flagp = (int*)(ws + OFF_FLAG);
    float* cembf = ws + OFF_CEMB;
    float* cWihf = ws + OFF_CWIH;
    float* cbihf = ws + OFF_CBIH;
    float* cbhhf = ws + OFF_CBHH;
    float* cWhhf = ws + OFF_CWHH;
    float* bihf  = ws + OFF_BIH;
    float* bhhf  = ws + OFF_BHH;
    float* W1T   = ws + OFF_W1T;
    float* cge   = ws + OFF_CGE;
    float* charh = ws + OFF_CH;
    __hip_bfloat16* xp2 = (__hip_bfloat16*)(ws + OFF_XP2);
    unsigned short* hh16 = (unsigned short*)(ws + OFF_HH);

    hipMemsetAsync(hh16, 0xFF, (size_t)4096 * 512 * 2, stream);

    detect_kernel<<<1, 64, 0, stream>>>((const unsigned*)char_emb, flagp);

    convf_kernel<<<(8192 + 255) / 256, 256, 0, stream>>>(char_emb, cembf, 8192, flagp);
    convf_kernel<<<(32768 + 255) / 256, 256, 0, stream>>>(char_Wih, cWihf, 32768, flagp);
    convf_kernel<<<2, 256, 0, stream>>>(char_bih, cbihf, 512, flagp);
    convf_kernel<<<2, 256, 0, stream>>>(char_bhh, cbhhf, 512, flagp);
    convf_kernel<<<(65536 + 255) / 256, 256, 0, stream>>>(char_Whh, cWhhf, 65536, flagp);
    convf_kernel<<<8, 256, 0, stream>>>(bih, bihf, 2048, flagp);
    convf_kernel<<<8, 256, 0, stream>>>(bhh, bhhf, 2048, flagp);
    w1t_kernel<<<128, 256, 0, stream>>>(W1, W1T, flagp);

    cge_kernel<<<128, 256, 0, stream>>>(cembf, cWihf, cbihf, cbhhf, cge);
    char_lstm_kernel<<<256, 256, 0, stream>>>(cge, cWhhf, chars, lens, charh);
    xp2_kernel<<<256, 256, 0, stream>>>(word_emb, x, charh, Wih, bihf, bhhf, xp2, flagp);
    word_lstm_kernel<<<16, 1024, 0, stream>>>(xp2, Whh, (unsigned*)hh16, flagp);
    out_kernel<<<4096, 64, 0, stream>>>(hh16, W1T, b1, d_out, flagp);
}

// Round 7
// 13334.232 us; speedup vs baseline: 1.0985x; 1.0383x over previous
//
#include <hip/hip_runtime.h>
#include <hip/hip_bf16.h>
#include <hip/hip_fp16.h>

// ---------------------------------------------------------------------------
// LSTMTagger: char-LSTM (4096x16, H=128) -> word-LSTM (serial 4096, H=512)
//             -> linear(64) + log_softmax.
// Wire dtype of float tensors detected at runtime (bf16 vs f32); kernels
// dual-path on device flag ws[0]: 1 = bf16, 0 = f32.
//
// Word LSTM (round 9, take 3 -- R6 failed on missing <hip/hip_fp16.h>):
//   16 WGs x 16 waves (proven topology), VALU/LDS diet.
//   R4 post-mortem: active-CU VALUBusy ~53% -> half the 2.5us step is issue,
//   not fabric. Fixes:
//   - h payload + Whh now packed f16 (pre-pass kernel): dot via
//     v_dot2_f32_f16 (__builtin_amdgcn_fdot2, guarded) = 8 ds_read_b128 +
//     32 dot2 per lane (was 16 reads + 64 FMA on f32), staging stores raw
//     dwords (no decode). f16 has MORE mantissa than bf16 -> accuracy up.
//   - weights = 8 uint4 pinned via in-loop asm (R1/R4 VGPR=52/56 proved the
//     outside-loop pin was ignored; loads were re-issued every step).
//   - R4's own-line LDS special case removed (uniform staging).
//   Protocol unchanged: 0xFFFFFFFF sentinel dwords (f16 NaN pair,
//   unreachable), ONE coalesced 64B line store per WG by wave0/lane<16,
//   hout[2] LDS double buffer, single barrier per step.
// ---------------------------------------------------------------------------

#define OFF_FLAG  0
#define OFF_CEMB  16
#define OFF_CWIH  8208
#define OFF_CBIH  40976
#define OFF_CBHH  41488
#define OFF_CWHH  42000
#define OFF_BIH   107536
#define OFF_BHH   109584
#define OFF_W1T   111632
#define OFF_CGE   144400
#define OFF_CH    209936
#define OFF_XP2   734224
#define OFF_HH    4928528
#define OFF_WHH16 5977104   /* word Whh as packed f16: 1048576 ushort = 2MB */

#define SENT 0xFFFFFFFFu

#ifndef __has_builtin
#define __has_builtin(x) 0
#endif
#if __has_builtin(__builtin_amdgcn_fdot2)
#define HASDOT2 1
#endif

typedef _Float16 v2h __attribute__((ext_vector_type(2)));

__device__ __forceinline__ float sigf(float x) { return 1.0f / (1.0f + __expf(-x)); }
__device__ __forceinline__ float tanh_f(float x) { return 2.0f * sigf(2.0f * x) - 1.0f; }
__device__ __forceinline__ float b2f_lo(unsigned u) { return __uint_as_float(u << 16); }
__device__ __forceinline__ float b2f_hi(unsigned u) { return __uint_as_float(u & 0xFFFF0000u); }
// f16 bits -> f32 via _Float16 (no header intrinsics needed)
__device__ __forceinline__ float h2f_lo(unsigned u) {
    union { unsigned short s; _Float16 h; } c;
    c.s = (unsigned short)(u & 0xFFFFu);
    return (float)c.h;
}
__device__ __forceinline__ float h2f_hi(unsigned u) {
    union { unsigned short s; _Float16 h; } c;
    c.s = (unsigned short)(u >> 16);
    return (float)c.h;
}
// f32 -> f16 bits (RNE via compiler _Float16 conversion)
__device__ __forceinline__ unsigned short f2h_bits(float f) {
    union { unsigned short s; _Float16 h; } c;
    c.h = (_Float16)f;
    return c.s;
}
// packed-f16 2-way dot: acc += w.lo*h.lo + w.hi*h.hi
__device__ __forceinline__ float dot2h(unsigned w, unsigned h, float acc) {
#ifdef HASDOT2
    union U { unsigned u; v2h v; };
    U uw; uw.u = w;
    U uh; uh.u = h;
    return __builtin_amdgcn_fdot2(uw.v, uh.v, acc, false);
#else
    return acc + h2f_lo(w) * h2f_lo(h) + h2f_hi(w) * h2f_hi(h);
#endif
}

// ---- D0: dtype detect. ---------------------------------------------------
__global__ void detect_kernel(const unsigned* __restrict__ w, int* __restrict__ flagp) {
    unsigned v = w[threadIdx.x];
    unsigned e = (v >> 7) & 0xFF;
    int inr = (e >= 100 && e <= 140) ? 1 : 0;
    unsigned long long m = __ballot(inr);
    if (threadIdx.x == 0) flagp[0] = (__popcll(m) >= 56) ? 1 : 0;
}

// ---- K0: (bf16|f32) -> f32 convert ---------------------------------------
__global__ void convf_kernel(const void* __restrict__ s, float* __restrict__ d,
                             int n, const int* __restrict__ flagp) {
    int i = blockIdx.x * 256 + threadIdx.x;
    if (i >= n) return;
    d[i] = flagp[0] ? __bfloat162float(((const __hip_bfloat16*)s)[i])
                    : ((const float*)s)[i];
}

// ---- K0b: W1 (64x512) -> W1T (512x64) f32 --------------------------------
__global__ void w1t_kernel(const void* __restrict__ W1, float* __restrict__ W1T,
                           const int* __restrict__ flagp) {
    int i = blockIdx.x * 256 + threadIdx.x;   // 0..32767
    int j = i & 63, k = i >> 6;
    W1T[i] = flagp[0] ? __bfloat162float(((const __hip_bfloat16*)W1)[j * 512 + k])
                      : ((const float*)W1)[j * 512 + k];
}

// ---- K0c: word Whh -> packed f16 -----------------------------------------
__global__ void whh16_kernel(const void* __restrict__ src, unsigned short* __restrict__ dst,
                             const int* __restrict__ flagp) {
    int i = blockIdx.x * 256 + threadIdx.x;   // 0..1048575
    float f = flagp[0] ? __bfloat162float(((const __hip_bfloat16*)src)[i])
                       : ((const float*)src)[i];
    dst[i] = f2h_bits(f);
}

// ---- K1: char gate table ------------------------------------------------
__global__ void __launch_bounds__(256) cge_kernel(
    const float* __restrict__ cemb, const float* __restrict__ cWih,
    const float* __restrict__ cbih, const float* __restrict__ cbhh,
    float* __restrict__ cge)
{
    __shared__ float xe[64];
    int c = blockIdx.x, tid = threadIdx.x;
    if (tid < 64) xe[tid] = cemb[c * 64 + tid];
    __syncthreads();
#pragma unroll
    for (int rep = 0; rep < 2; ++rep) {
        int j = rep * 256 + tid;
        float acc = cbih[j] + cbhh[j];
#pragma unroll 8
        for (int k = 0; k < 64; ++k)
            acc += xe[k] * cWih[j * 64 + k];
        cge[c * 512 + j] = acc;
    }
}

// ---- K2: char LSTM -------------------------------------------------------
__global__ void __launch_bounds__(256) char_lstm_kernel(
    const float* __restrict__ cge, const float* __restrict__ Whh,
    const int* __restrict__ chars, const int* __restrict__ lens,
    float* __restrict__ char_h)
{
    __shared__ float hls[16][128];
    int tid = threadIdx.x;
    int wl = tid >> 4, sl = tid & 15;
    int w = blockIdx.x * 16 + wl;
    int len = lens[w];
    const int* cw = chars + w * 16;
    float c[8];
#pragma unroll
    for (int q = 0; q < 8; ++q) { c[q] = 0.0f; hls[wl][sl * 8 + q] = 0.0f; }

    for (int t = 0; t < 16; ++t) {
        __syncthreads();
        int ch = cw[t];
        const float* xg = cge + ch * 512;
        float acc[4][8];
#pragma unroll
        for (int g = 0; g < 4; ++g)
#pragma unroll
            for (int q = 0; q < 8; ++q)
                acc[g][q] = xg[g * 128 + sl * 8 + q];

        const float4* h4 = (const float4*)hls[wl];
#pragma unroll
        for (int g = 0; g < 4; ++g) {
            const float4* wbase = ((const float4*)Whh) + (g * 128 + sl * 8) * 32;
            for (int k4 = 0; k4 < 32; ++k4) {
                float4 hv = h4[k4];
#pragma unroll
                for (int q = 0; q < 8; ++q) {
                    float4 wv = wbase[q * 32 + k4];
                    acc[g][q] += wv.x * hv.x + wv.y * hv.y + wv.z * hv.z + wv.w * hv.w;
                }
            }
        }
        __syncthreads();
        if (t < len) {
#pragma unroll
            for (int q = 0; q < 8; ++q) {
                float iv = sigf(acc[0][q]);
                float fv = sigf(acc[1][q]);
                float gv = tanh_f(acc[2][q]);
                float ov = sigf(acc[3][q]);
                c[q] = fv * c[q] + iv * gv;
                hls[wl][sl * 8 + q] = ov * tanh_f(c[q]);
            }
        }
    }
    __syncthreads();
#pragma unroll
    for (int q = 0; q < 8; ++q)
        char_h[w * 128 + sl * 8 + q] = hls[wl][sl * 8 + q];
}

// ---- K3: word x-part gates (bf16 out) ------------------------------------
__global__ void __launch_bounds__(256) xp2_kernel(
    const void* __restrict__ wemb, const int* __restrict__ x,
    const float* __restrict__ char_h, const void* __restrict__ Wraw,
    const float* __restrict__ bih, const float* __restrict__ bhh,
    __hip_bfloat16* __restrict__ xp2, const int* __restrict__ flagp)
{
    __shared__ float feat[16][384];
    int flag = flagp[0];
    int tid = threadIdx.x, tl = tid >> 4, sl = tid & 15;
    int t = blockIdx.x * 16 + tl;
    int xw = x[t];
    for (int idx = sl; idx < 384; idx += 16) {
        float v;
        if (idx < 256)
            v = flag ? __bfloat162float(((const __hip_bfloat16*)wemb)[(size_t)xw * 256 + idx])
                     : ((const float*)wemb)[(size_t)xw * 256 + idx];
        else
            v = char_h[t * 128 + (idx - 256)];
        feat[tl][idx] = v;
    }
    __syncthreads();

    const float4* f4 = (const float4*)feat[tl];
    for (int rb = 0; rb < 4; ++rb) {
        int r0 = rb * 512 + sl * 32;
        for (int qc = 0; qc < 4; ++qc) {
            int rr = r0 + qc * 8;
            float acc[8];
#pragma unroll
            for (int q = 0; q < 8; ++q)
                acc[q] = bih[rr + q] + bhh[rr + q];
            if (!flag) {
                const float4* wb = ((const float4*)Wraw) + (size_t)rr * 96;
                for (int k4 = 0; k4 < 96; ++k4) {
                    float4 fv = f4[k4];
#pragma unroll
                    for (int q = 0; q < 8; ++q) {
                        float4 wv = wb[q * 96 + k4];
                        acc[q] += wv.x * fv.x + wv.y * fv.y + wv.z * fv.z + wv.w * fv.w;
                    }
                }
            } else {
                const uint2* wb = ((const uint2*)Wraw) + (size_t)rr * 96;
                for (int k4 = 0; k4 < 96; ++k4) {
                    float4 fv = f4[k4];
#pragma unroll
                    for (int q = 0; q < 8; ++q) {
                        uint2 wv = wb[q * 96 + k4];
                        acc[q] += b2f_lo(wv.x) * fv.x + b2f_hi(wv.x) * fv.y
                                + b2f_lo(wv.y) * fv.z + b2f_hi(wv.y) * fv.w;
                    }
                }
            }
#pragma unroll
            for (int q = 0; q < 8; ++q)
                xp2[(size_t)t * 2048 + rr + q] = __float2bfloat16(acc[q]);
        }
    }
}

// ---- K5: serial word LSTM (16 WGs, f16 payload, v_dot2 inner) ------------
__global__ void __launch_bounds__(1024, 4) word_lstm_kernel(
    const __hip_bfloat16* __restrict__ xp2, const unsigned* __restrict__ whh16,
    unsigned* __restrict__ hview)
{
    // raw f16x2 dwords; 16 chunks x (16 + 4 pad) dwords -> b128 reads are
    // 16B-aligned, bank aliasing <= 2-way (free)
    __shared__ unsigned hbuf[16][320];
    __shared__ float hout[2][32];    // double-buffered fresh h (f32)
    int wg = blockIdx.x;
    int tid = threadIdx.x;
    int wave = tid >> 6, lane = tid & 63;
    int sp = lane >> 5;              // sub-slot 0/1 within the wave
    int g  = (lane >> 3) & 3;        // gate i/f/g/o
    int kk = lane & 7;               // k-chunk (64 h-values wide)
    int slot = wg * 32 + wave * 2 + sp;
    int grow = g * 512 + slot;

    // weights: Whh[grow][kk*64 .. +63] as 32 packed-f16 dwords = 8 uint4
    const uint4* wr = (const uint4*)(whh16 + (size_t)grow * 256) + kk * 8;
    uint4 wa0 = wr[0], wa1 = wr[1], wa2 = wr[2], wa3 = wr[3];
    uint4 wa4 = wr[4], wa5 = wr[5], wa6 = wr[6], wa7 = wr[7];

    const unsigned short* xpr = (const unsigned short*)xp2;
    unsigned* wbuf = hbuf[wave];
    float c = 0.0f;
    int dead = 0;                    // sticky anti-hang

#define PINU4(a) asm volatile("" : "+v"(a.x), "+v"(a.y), "+v"(a.z), "+v"(a.w))
    for (int t = 0; t < 4096; ++t) {
        // h-independent: issue before the poll so latency hides under the spin
        unsigned short xraw = xpr[(size_t)t * 2048 + grow];
        // in-loop pin: forces the 32 weight dwords to stay register-resident
        // across iterations (outside-loop pin was ignored; VGPR=56 showed
        // per-step reloads)
        PINU4(wa0); PINU4(wa1); PINU4(wa2); PINU4(wa3);
        PINU4(wa4); PINU4(wa5); PINU4(wa6); PINU4(wa7);

        if (t == 0) {
            // h_{-1} = 0 (f16 zero pair = 0x00000000)
#pragma unroll
            for (int i = 0; i < 4; ++i)
                wbuf[((lane >> 4) + 4 * i) * 20 + (lane & 15)] = 0u;
        } else {
            // poll h_{t-1}: lane l covers dwords l+64i (coalesced 256B/instr)
            const unsigned* src = hview + (size_t)(t - 1) * 256 + lane;
            unsigned v[4];
            unsigned spins = 0;
            for (;;) {
#pragma unroll
                for (int i = 0; i < 4; ++i)
                    v[i] = __hip_atomic_load(src + i * 64, __ATOMIC_RELAXED,
                                             __HIP_MEMORY_SCOPE_AGENT);
                int ok = 1;
#pragma unroll
                for (int i = 0; i < 4; ++i) ok &= (v[i] != SENT);
                if (dead || __all(ok)) break;
                if (++spins > (1u << 22)) { dead = 1; break; }
            }
            if (dead) {
#pragma unroll
                for (int i = 0; i < 4; ++i)
                    if (v[i] == SENT) v[i] = 0x3C003C00u;   // f16 1.0 pair
            }
            // stage raw dwords: d = lane+64i -> chunk d>>4, offset d&15
#pragma unroll
            for (int i = 0; i < 4; ++i)
                wbuf[((lane >> 4) + 4 * i) * 20 + (lane & 15)] = v[i];
        }

        // dot: h[kk*64 .. +63] . w  -- 8 b128 reads + 32 v_dot2_f32_f16,
        // 4 independent accumulator chains
        const uint4* q0 = (const uint4*)(wbuf + (2 * kk) * 20);
        const uint4* q1 = (const uint4*)(wbuf + (2 * kk) * 20 + 20);
        float a0 = 0.0f, a1 = 0.0f, a2 = 0.0f, a3 = 0.0f;
        uint4 h4;
        h4 = q0[0]; a0 = dot2h(wa0.x, h4.x, a0); a1 = dot2h(wa0.y, h4.y, a1);
                    a2 = dot2h(wa0.z, h4.z, a2); a3 = dot2h(wa0.w, h4.w, a3);
        h4 = q0[1]; a0 = dot2h(wa1.x, h4.x, a0); a1 = dot2h(wa1.y, h4.y, a1);
                    a2 = dot2h(wa1.z, h4.z, a2); a3 = dot2h(wa1.w, h4.w, a3);
        h4 = q0[2]; a0 = dot2h(wa2.x, h4.x, a0); a1 = dot2h(wa2.y, h4.y, a1);
                    a2 = dot2h(wa2.z, h4.z, a2); a3 = dot2h(wa2.w, h4.w, a3);
        h4 = q0[3]; a0 = dot2h(wa3.x, h4.x, a0); a1 = dot2h(wa3.y, h4.y, a1);
                    a2 = dot2h(wa3.z, h4.z, a2); a3 = dot2h(wa3.w, h4.w, a3);
        h4 = q1[0]; a0 = dot2h(wa4.x, h4.x, a0); a1 = dot2h(wa4.y, h4.y, a1);
                    a2 = dot2h(wa4.z, h4.z, a2); a3 = dot2h(wa4.w, h4.w, a3);
        h4 = q1[1]; a0 = dot2h(wa5.x, h4.x, a0); a1 = dot2h(wa5.y, h4.y, a1);
                    a2 = dot2h(wa5.z, h4.z, a2); a3 = dot2h(wa5.w, h4.w, a3);
        h4 = q1[2]; a0 = dot2h(wa6.x, h4.x, a0); a1 = dot2h(wa6.y, h4.y, a1);
                    a2 = dot2h(wa6.z, h4.z, a2); a3 = dot2h(wa6.w, h4.w, a3);
        h4 = q1[3]; a0 = dot2h(wa7.x, h4.x, a0); a1 = dot2h(wa7.y, h4.y, a1);
                    a2 = dot2h(wa7.z, h4.z, a2); a3 = dot2h(wa7.w, h4.w, a3);
        float acc = (a0 + a1) + (a2 + a3);
        acc += __shfl_xor(acc, 1);
        acc += __shfl_xor(acc, 2);
        acc += __shfl_xor(acc, 4);
        float gvt = acc + __bfloat162float(*(const __hip_bfloat16*)&xraw);

        float iv = __shfl(gvt, sp * 32 + 0);
        float fv = __shfl(gvt, sp * 32 + 8);
        float gg = __shfl(gvt, sp * 32 + 16);
        float ov = __shfl(gvt, sp * 32 + 24);
        c = sigf(fv) * c + sigf(iv) * tanh_f(gg);
        float h = sigf(ov) * tanh_f(c);

        if ((lane & 31) == 0) hout[t & 1][wave * 2 + sp] = h;
        __syncthreads();                 // hout complete

        if (wave == 0 && lane < 16) {
            // pack 2 h -> f16x2 dword; ONE 64B-line store for the whole WG
            unsigned u0 = f2h_bits(hout[t & 1][2 * lane]);
            unsigned u1 = f2h_bits(hout[t & 1][2 * lane + 1]);
            __hip_atomic_store(hview + (size_t)t * 256 + wg * 16 + lane,
                               u0 | (u1 << 16),
                               __ATOMIC_RELAXED, __HIP_MEMORY_SCOPE_AGENT);
        }
        // no trailing barrier: hout[t&1] is next written at t+2 (other buffer
        // at t+1); reaching t+2 implies all waves passed the t+1 barrier.
    }
#undef PINU4
}

// ---- K6: logits + log_softmax (h_hist is f16) ----------------------------
__global__ void __launch_bounds__(64) out_kernel(
    const unsigned short* __restrict__ hh16, const float* __restrict__ W1T,
    const void* __restrict__ b1raw, void* __restrict__ out,
    const int* __restrict__ flagp)
{
    __shared__ float hb[512];
    int flag = flagp[0];
    int t = blockIdx.x, j = threadIdx.x;
    const unsigned* src = (const unsigned*)(hh16 + (size_t)t * 512);
#pragma unroll
    for (int kq = 0; kq < 4; ++kq) {
        unsigned u = src[j * 4 + kq];
        hb[j * 8 + 2 * kq]     = h2f_lo(u);
        hb[j * 8 + 2 * kq + 1] = h2f_hi(u);
    }
    __syncthreads();

    float acc = flag ? __bfloat162float(((const __hip_bfloat16*)b1raw)[j])
                     : ((const float*)b1raw)[j];
#pragma unroll 8
    for (int k = 0; k < 512; ++k)
        acc += hb[k] * W1T[k * 64 + j];

    float m = acc;
#pragma unroll
    for (int o = 32; o; o >>= 1) m = fmaxf(m, __shfl_xor(m, o));
    float e = __expf(acc - m);
    float s = e;
#pragma unroll
    for (int o = 32; o; o >>= 1) s += __shfl_xor(s, o);
    float r = acc - m - __logf(s);
    if (flag) ((__hip_bfloat16*)out)[t * 64 + j] = __float2bfloat16(r);
    else      ((float*)out)[t * 64 + j] = r;
}

extern "C" void kernel_launch(void* const* d_in, const int* in_sizes, int n_in,
                              void* d_out, int out_size, void* d_ws, size_t ws_size,
                              hipStream_t stream)
{
    (void)in_sizes; (void)n_in; (void)out_size; (void)ws_size;
    const void* char_emb = d_in[0];
    const void* char_Wih = d_in[1];
    const void* char_Whh = d_in[2];
    const void* char_bih = d_in[3];
    const void* char_bhh = d_in[4];
    const void* word_emb = d_in[5];
    const void* Wih      = d_in[6];
    const void* Whh      = d_in[7];
    const void* bih      = d_in[8];
    const void* bhh      = d_in[9];
    const void* W1       = d_in[10];
    const void* b1       = d_in[11];
    const int* x     = (const int*)d_in[12];
    const int* chars = (const int*)d_in[13];
    const int* lens  = (const int*)d_in[14];

    float* ws    = (float*)d_ws;
    int*   flagp = (int*)(ws + OFF_FLAG);
    float* cembf = ws + OFF_CEMB;
    float* cWihf = ws + OFF_CWIH;
    float* cbihf = ws + OFF_CBIH;
    float* cbhhf = ws + OFF_CBHH;
    float* cWhhf = ws + OFF_CWHH;
    float* bihf  = ws + OFF_BIH;
    float* bhhf  = ws + OFF_BHH;
    float* W1T   = ws + OFF_W1T;
    float* cge   = ws + OFF_CGE;
    float* charh = ws + OFF_CH;
    __hip_bfloat16* xp2 = (__hip_bfloat16*)(ws + OFF_XP2);
    unsigned short* hh16 = (unsigned short*)(ws + OFF_HH);
    unsigned short* whh16 = (unsigned short*)(ws + OFF_WHH16);

    (void)hipMemsetAsync(hh16, 0xFF, (size_t)4096 * 512 * 2, stream);

    detect_kernel<<<1, 64, 0, stream>>>((const unsigned*)char_emb, flagp);

    convf_kernel<<<(8192 + 255) / 256, 256, 0, stream>>>(char_emb, cembf, 8192, flagp);
    convf_kernel<<<(32768 + 255) / 256, 256, 0, stream>>>(char_Wih, cWihf, 32768, flagp);
    convf_kernel<<<2, 256, 0, stream>>>(char_bih, cbihf, 512, flagp);
    convf_kernel<<<2, 256, 0, stream>>>(char_bhh, cbhhf, 512, flagp);
    convf_kernel<<<(65536 + 255) / 256, 256, 0, stream>>>(char_Whh, cWhhf, 65536, flagp);
    convf_kernel<<<8, 256, 0, stream>>>(bih, bihf, 2048, flagp);
    convf_kernel<<<8, 256, 0, stream>>>(bhh, bhhf, 2048, flagp);
    w1t_kernel<<<128, 256, 0, stream>>>(W1, W1T, flagp);
    whh16_kernel<<<4096, 256, 0, stream>>>(Whh, whh16, flagp);

    cge_kernel<<<128, 256, 0, stream>>>(cembf, cWihf, cbihf, cbhhf, cge);
    char_lstm_kernel<<<256, 256, 0, stream>>>(cge, cWhhf, chars, lens, charh);
    xp2_kernel<<<256, 256, 0, stream>>>(word_emb, x, charh, Wih, bihf, bhhf, xp2, flagp);
    word_lstm_kernel<<<16, 1024, 0, stream>>>(xp2, (const unsigned*)whh16, (unsigned*)hh16);
    out_kernel<<<4096, 64, 0, stream>>>(hh16, W1T, b1, d_out, flagp);
}

// Round 8
// 12754.176 us; speedup vs baseline: 1.1485x; 1.0455x over previous
//
#include <hip/hip_runtime.h>
#include <hip/hip_bf16.h>
#include <hip/hip_fp16.h>

// ---------------------------------------------------------------------------
// LSTMTagger: char-LSTM (4096x16, H=128) -> word-LSTM (serial 4096, H=512)
//             -> linear(64) + log_softmax.
// Wire dtype of float tensors detected at runtime (bf16 vs f32); kernels
// dual-path on device flag ws[0]: 1 = bf16, 0 = f32.
//
// Word LSTM (round 10): register + LDS-bank repair of the R7 f16 kernel.
//   R7 counters exposed two self-inflicted wounds:
//   - VGPR_Count=32 == 512/(16 waves/SIMD): __launch_bounds__(1024,4) was
//     applied with CUDA "min blocks/CU" semantics -> 4 blocks x 16 waves =
//     16 waves/SIMD -> 32-VGPR cap. The 32 weight dwords could NEVER be
//     resident; every step re-streamed weights from L2 inside the serial
//     loop. Only 1 WG/CU ever runs, so the bound bought nothing.
//     FIX: __launch_bounds__(1024, 1) -> 128-VGPR cap.
//   - SQ_LDS_BANK_CONFLICT=2^23: stride-20 chunks collide for kk vs kk+4
//     (banks 40kk%32 period 4) on every ds_read_b128.
//     FIX: split staging into TWO arrays A (even chunks) / B (odd chunks),
//     each 8 chunks x 20 dwords: read banks kk*20%32 =
//     {0,20,8,28,16,4,24,12} -> all distinct -> conflict-free b128; both
//     reads stay 16B-aligned; writes <=2-way on 4 banks (free).
//   Protocol unchanged (proven R1 topology): 16 WGs x 16 waves, 0xFFFFFFFF
//   sentinel dwords, ONE coalesced 64B line store per WG by wave0/lane<16,
//   hout[2] LDS double buffer, single barrier per step, f16 payload,
//   v_dot2_f32_f16 inner product.
// ---------------------------------------------------------------------------

#define OFF_FLAG  0
#define OFF_CEMB  16
#define OFF_CWIH  8208
#define OFF_CBIH  40976
#define OFF_CBHH  41488
#define OFF_CWHH  42000
#define OFF_BIH   107536
#define OFF_BHH   109584
#define OFF_W1T   111632
#define OFF_CGE   144400
#define OFF_CH    209936
#define OFF_XP2   734224
#define OFF_HH    4928528
#define OFF_WHH16 5977104   /* word Whh as packed f16: 1048576 ushort = 2MB */

#define SENT 0xFFFFFFFFu

#ifndef __has_builtin
#define __has_builtin(x) 0
#endif
#if __has_builtin(__builtin_amdgcn_fdot2)
#define HASDOT2 1
#endif

typedef _Float16 v2h __attribute__((ext_vector_type(2)));

__device__ __forceinline__ float sigf(float x) { return 1.0f / (1.0f + __expf(-x)); }
__device__ __forceinline__ float tanh_f(float x) { return 2.0f * sigf(2.0f * x) - 1.0f; }
__device__ __forceinline__ float b2f_lo(unsigned u) { return __uint_as_float(u << 16); }
__device__ __forceinline__ float b2f_hi(unsigned u) { return __uint_as_float(u & 0xFFFF0000u); }
// f16 bits -> f32 via _Float16 (no header intrinsics needed)
__device__ __forceinline__ float h2f_lo(unsigned u) {
    union { unsigned short s; _Float16 h; } c;
    c.s = (unsigned short)(u & 0xFFFFu);
    return (float)c.h;
}
__device__ __forceinline__ float h2f_hi(unsigned u) {
    union { unsigned short s; _Float16 h; } c;
    c.s = (unsigned short)(u >> 16);
    return (float)c.h;
}
// f32 -> f16 bits (RNE via compiler _Float16 conversion)
__device__ __forceinline__ unsigned short f2h_bits(float f) {
    union { unsigned short s; _Float16 h; } c;
    c.h = (_Float16)f;
    return c.s;
}
// packed-f16 2-way dot: acc += w.lo*h.lo + w.hi*h.hi
__device__ __forceinline__ float dot2h(unsigned w, unsigned h, float acc) {
#ifdef HASDOT2
    union U { unsigned u; v2h v; };
    U uw; uw.u = w;
    U uh; uh.u = h;
    return __builtin_amdgcn_fdot2(uw.v, uh.v, acc, false);
#else
    return acc + h2f_lo(w) * h2f_lo(h) + h2f_hi(w) * h2f_hi(h);
#endif
}

// ---- D0: dtype detect. ---------------------------------------------------
__global__ void detect_kernel(const unsigned* __restrict__ w, int* __restrict__ flagp) {
    unsigned v = w[threadIdx.x];
    unsigned e = (v >> 7) & 0xFF;
    int inr = (e >= 100 && e <= 140) ? 1 : 0;
    unsigned long long m = __ballot(inr);
    if (threadIdx.x == 0) flagp[0] = (__popcll(m) >= 56) ? 1 : 0;
}

// ---- K0: (bf16|f32) -> f32 convert ---------------------------------------
__global__ void convf_kernel(const void* __restrict__ s, float* __restrict__ d,
                             int n, const int* __restrict__ flagp) {
    int i = blockIdx.x * 256 + threadIdx.x;
    if (i >= n) return;
    d[i] = flagp[0] ? __bfloat162float(((const __hip_bfloat16*)s)[i])
                    : ((const float*)s)[i];
}

// ---- K0b: W1 (64x512) -> W1T (512x64) f32 --------------------------------
__global__ void w1t_kernel(const void* __restrict__ W1, float* __restrict__ W1T,
                           const int* __restrict__ flagp) {
    int i = blockIdx.x * 256 + threadIdx.x;   // 0..32767
    int j = i & 63, k = i >> 6;
    W1T[i] = flagp[0] ? __bfloat162float(((const __hip_bfloat16*)W1)[j * 512 + k])
                      : ((const float*)W1)[j * 512 + k];
}

// ---- K0c: word Whh -> packed f16 -----------------------------------------
__global__ void whh16_kernel(const void* __restrict__ src, unsigned short* __restrict__ dst,
                             const int* __restrict__ flagp) {
    int i = blockIdx.x * 256 + threadIdx.x;   // 0..1048575
    float f = flagp[0] ? __bfloat162float(((const __hip_bfloat16*)src)[i])
                       : ((const float*)src)[i];
    dst[i] = f2h_bits(f);
}

// ---- K1: char gate table ------------------------------------------------
__global__ void __launch_bounds__(256) cge_kernel(
    const float* __restrict__ cemb, const float* __restrict__ cWih,
    const float* __restrict__ cbih, const float* __restrict__ cbhh,
    float* __restrict__ cge)
{
    __shared__ float xe[64];
    int c = blockIdx.x, tid = threadIdx.x;
    if (tid < 64) xe[tid] = cemb[c * 64 + tid];
    __syncthreads();
#pragma unroll
    for (int rep = 0; rep < 2; ++rep) {
        int j = rep * 256 + tid;
        float acc = cbih[j] + cbhh[j];
#pragma unroll 8
        for (int k = 0; k < 64; ++k)
            acc += xe[k] * cWih[j * 64 + k];
        cge[c * 512 + j] = acc;
    }
}

// ---- K2: char LSTM -------------------------------------------------------
__global__ void __launch_bounds__(256) char_lstm_kernel(
    const float* __restrict__ cge, const float* __restrict__ Whh,
    const int* __restrict__ chars, const int* __restrict__ lens,
    float* __restrict__ char_h)
{
    __shared__ float hls[16][128];
    int tid = threadIdx.x;
    int wl = tid >> 4, sl = tid & 15;
    int w = blockIdx.x * 16 + wl;
    int len = lens[w];
    const int* cw = chars + w * 16;
    float c[8];
#pragma unroll
    for (int q = 0; q < 8; ++q) { c[q] = 0.0f; hls[wl][sl * 8 + q] = 0.0f; }

    for (int t = 0; t < 16; ++t) {
        __syncthreads();
        int ch = cw[t];
        const float* xg = cge + ch * 512;
        float acc[4][8];
#pragma unroll
        for (int g = 0; g < 4; ++g)
#pragma unroll
            for (int q = 0; q < 8; ++q)
                acc[g][q] = xg[g * 128 + sl * 8 + q];

        const float4* h4 = (const float4*)hls[wl];
#pragma unroll
        for (int g = 0; g < 4; ++g) {
            const float4* wbase = ((const float4*)Whh) + (g * 128 + sl * 8) * 32;
            for (int k4 = 0; k4 < 32; ++k4) {
                float4 hv = h4[k4];
#pragma unroll
                for (int q = 0; q < 8; ++q) {
                    float4 wv = wbase[q * 32 + k4];
                    acc[g][q] += wv.x * hv.x + wv.y * hv.y + wv.z * hv.z + wv.w * hv.w;
                }
            }
        }
        __syncthreads();
        if (t < len) {
#pragma unroll
            for (int q = 0; q < 8; ++q) {
                float iv = sigf(acc[0][q]);
                float fv = sigf(acc[1][q]);
                float gv = tanh_f(acc[2][q]);
                float ov = sigf(acc[3][q]);
                c[q] = fv * c[q] + iv * gv;
                hls[wl][sl * 8 + q] = ov * tanh_f(c[q]);
            }
        }
    }
    __syncthreads();
#pragma unroll
    for (int q = 0; q < 8; ++q)
        char_h[w * 128 + sl * 8 + q] = hls[wl][sl * 8 + q];
}

// ---- K3: word x-part gates (bf16 out) ------------------------------------
__global__ void __launch_bounds__(256) xp2_kernel(
    const void* __restrict__ wemb, const int* __restrict__ x,
    const float* __restrict__ char_h, const void* __restrict__ Wraw,
    const float* __restrict__ bih, const float* __restrict__ bhh,
    __hip_bfloat16* __restrict__ xp2, const int* __restrict__ flagp)
{
    __shared__ float feat[16][384];
    int flag = flagp[0];
    int tid = threadIdx.x, tl = tid >> 4, sl = tid & 15;
    int t = blockIdx.x * 16 + tl;
    int xw = x[t];
    for (int idx = sl; idx < 384; idx += 16) {
        float v;
        if (idx < 256)
            v = flag ? __bfloat162float(((const __hip_bfloat16*)wemb)[(size_t)xw * 256 + idx])
                     : ((const float*)wemb)[(size_t)xw * 256 + idx];
        else
            v = char_h[t * 128 + (idx - 256)];
        feat[tl][idx] = v;
    }
    __syncthreads();

    const float4* f4 = (const float4*)feat[tl];
    for (int rb = 0; rb < 4; ++rb) {
        int r0 = rb * 512 + sl * 32;
        for (int qc = 0; qc < 4; ++qc) {
            int rr = r0 + qc * 8;
            float acc[8];
#pragma unroll
            for (int q = 0; q < 8; ++q)
                acc[q] = bih[rr + q] + bhh[rr + q];
            if (!flag) {
                const float4* wb = ((const float4*)Wraw) + (size_t)rr * 96;
                for (int k4 = 0; k4 < 96; ++k4) {
                    float4 fv = f4[k4];
#pragma unroll
                    for (int q = 0; q < 8; ++q) {
                        float4 wv = wb[q * 96 + k4];
                        acc[q] += wv.x * fv.x + wv.y * fv.y + wv.z * fv.z + wv.w * fv.w;
                    }
                }
            } else {
                const uint2* wb = ((const uint2*)Wraw) + (size_t)rr * 96;
                for (int k4 = 0; k4 < 96; ++k4) {
                    float4 fv = f4[k4];
#pragma unroll
                    for (int q = 0; q < 8; ++q) {
                        uint2 wv = wb[q * 96 + k4];
                        acc[q] += b2f_lo(wv.x) * fv.x + b2f_hi(wv.x) * fv.y
                                + b2f_lo(wv.y) * fv.z + b2f_hi(wv.y) * fv.w;
                    }
                }
            }
#pragma unroll
            for (int q = 0; q < 8; ++q)
                xp2[(size_t)t * 2048 + rr + q] = __float2bfloat16(acc[q]);
        }
    }
}

// ---- K5: serial word LSTM (16 WGs, f16 payload, conflict-free LDS) -------
__global__ void __launch_bounds__(1024, 1) word_lstm_kernel(
    const __hip_bfloat16* __restrict__ xp2, const unsigned* __restrict__ whh16,
    unsigned* __restrict__ hview)
{
    // Split staging: A holds even chunks (2m), B holds odd (2m+1); 8 chunks
    // x 20 dwords (16 data + 4 pad) per wave. Read base kk*20 -> banks
    // {0,20,8,28,16,4,24,12}: all 8 kk distinct -> conflict-free b128.
    __shared__ __align__(16) unsigned hbufA[16][160];
    __shared__ __align__(16) unsigned hbufB[16][160];
    __shared__ float hout[2][32];    // double-buffered fresh h (f32)
    int wg = blockIdx.x;
    int tid = threadIdx.x;
    int wave = tid >> 6, lane = tid & 63;
    int sp = lane >> 5;              // sub-slot 0/1 within the wave
    int g  = (lane >> 3) & 3;        // gate i/f/g/o
    int kk = lane & 7;               // k-chunk (64 h-values wide)
    int slot = wg * 32 + wave * 2 + sp;
    int grow = g * 512 + slot;

    // weights: Whh[grow][kk*64 .. +63] as 32 packed-f16 dwords = 8 uint4
    const uint4* wr = (const uint4*)(whh16 + (size_t)grow * 256) + kk * 8;
    uint4 wa0 = wr[0], wa1 = wr[1], wa2 = wr[2], wa3 = wr[3];
    uint4 wa4 = wr[4], wa5 = wr[5], wa6 = wr[6], wa7 = wr[7];

    const unsigned short* xpr = (const unsigned short*)xp2;
    unsigned* wbA = hbufA[wave];
    unsigned* wbB = hbufB[wave];
    // write routing: value dword d = lane+64i -> chunk j+4i (j=lane>>4),
    // parity j&1 selects array, index (j>>1)+2i, offset lane&15
    unsigned* wdst = ((lane >> 4) & 1) ? wbB : wbA;
    int hj = (lane >> 4) >> 1;       // 0 or 1
    float c = 0.0f;
    int dead = 0;                    // sticky anti-hang

#define PINU4(a) asm volatile("" : "+v"(a.x), "+v"(a.y), "+v"(a.z), "+v"(a.w))
    for (int t = 0; t < 4096; ++t) {
        // h-independent: issue before the poll so latency hides under the spin
        unsigned short xraw = xpr[(size_t)t * 2048 + grow];
        // in-loop pin: with the 128-VGPR cap (launch_bounds fix) the 32
        // weight dwords can now actually STAY resident across iterations
        PINU4(wa0); PINU4(wa1); PINU4(wa2); PINU4(wa3);
        PINU4(wa4); PINU4(wa5); PINU4(wa6); PINU4(wa7);

        if (t == 0) {
            // h_{-1} = 0 (f16 zero pair = 0x00000000)
#pragma unroll
            for (int i = 0; i < 4; ++i)
                wdst[(hj + 2 * i) * 20 + (lane & 15)] = 0u;
        } else {
            // poll h_{t-1}: lane l covers dwords l+64i (coalesced 256B/instr)
            const unsigned* src = hview + (size_t)(t - 1) * 256 + lane;
            unsigned v[4];
            unsigned spins = 0;
            for (;;) {
#pragma unroll
                for (int i = 0; i < 4; ++i)
                    v[i] = __hip_atomic_load(src + i * 64, __ATOMIC_RELAXED,
                                             __HIP_MEMORY_SCOPE_AGENT);
                int ok = 1;
#pragma unroll
                for (int i = 0; i < 4; ++i) ok &= (v[i] != SENT);
                if (dead || __all(ok)) break;
                if (++spins > (1u << 22)) { dead = 1; break; }
            }
            if (dead) {
#pragma unroll
                for (int i = 0; i < 4; ++i)
                    if (v[i] == SENT) v[i] = 0x3C003C00u;   // f16 1.0 pair
            }
            // stage raw dwords into split A/B layout
#pragma unroll
            for (int i = 0; i < 4; ++i)
                wdst[(hj + 2 * i) * 20 + (lane & 15)] = v[i];
        }

        // dot: h[kk*64 .. +63] . w  -- A[kk] = chunk 2kk, B[kk] = chunk 2kk+1,
        // 8 conflict-free b128 reads + 32 v_dot2_f32_f16, 4 acc chains
        const uint4* q0 = (const uint4*)(wbA + kk * 20);
        const uint4* q1 = (const uint4*)(wbB + kk * 20);
        float a0 = 0.0f, a1 = 0.0f, a2 = 0.0f, a3 = 0.0f;
        uint4 h4;
        h4 = q0[0]; a0 = dot2h(wa0.x, h4.x, a0); a1 = dot2h(wa0.y, h4.y, a1);
                    a2 = dot2h(wa0.z, h4.z, a2); a3 = dot2h(wa0.w, h4.w, a3);
        h4 = q0[1]; a0 = dot2h(wa1.x, h4.x, a0); a1 = dot2h(wa1.y, h4.y, a1);
                    a2 = dot2h(wa1.z, h4.z, a2); a3 = dot2h(wa1.w, h4.w, a3);
        h4 = q0[2]; a0 = dot2h(wa2.x, h4.x, a0); a1 = dot2h(wa2.y, h4.y, a1);
                    a2 = dot2h(wa2.z, h4.z, a2); a3 = dot2h(wa2.w, h4.w, a3);
        h4 = q0[3]; a0 = dot2h(wa3.x, h4.x, a0); a1 = dot2h(wa3.y, h4.y, a1);
                    a2 = dot2h(wa3.z, h4.z, a2); a3 = dot2h(wa3.w, h4.w, a3);
        h4 = q1[0]; a0 = dot2h(wa4.x, h4.x, a0); a1 = dot2h(wa4.y, h4.y, a1);
                    a2 = dot2h(wa4.z, h4.z, a2); a3 = dot2h(wa4.w, h4.w, a3);
        h4 = q1[1]; a0 = dot2h(wa5.x, h4.x, a0); a1 = dot2h(wa5.y, h4.y, a1);
                    a2 = dot2h(wa5.z, h4.z, a2); a3 = dot2h(wa5.w, h4.w, a3);
        h4 = q1[2]; a0 = dot2h(wa6.x, h4.x, a0); a1 = dot2h(wa6.y, h4.y, a1);
                    a2 = dot2h(wa6.z, h4.z, a2); a3 = dot2h(wa6.w, h4.w, a3);
        h4 = q1[3]; a0 = dot2h(wa7.x, h4.x, a0); a1 = dot2h(wa7.y, h4.y, a1);
                    a2 = dot2h(wa7.z, h4.z, a2); a3 = dot2h(wa7.w, h4.w, a3);
        float acc = (a0 + a1) + (a2 + a3);
        acc += __shfl_xor(acc, 1);
        acc += __shfl_xor(acc, 2);
        acc += __shfl_xor(acc, 4);
        float gvt = acc + __bfloat162float(*(const __hip_bfloat16*)&xraw);

        float iv = __shfl(gvt, sp * 32 + 0);
        float fv = __shfl(gvt, sp * 32 + 8);
        float gg = __shfl(gvt, sp * 32 + 16);
        float ov = __shfl(gvt, sp * 32 + 24);
        c = sigf(fv) * c + sigf(iv) * tanh_f(gg);
        float h = sigf(ov) * tanh_f(c);

        if ((lane & 31) == 0) hout[t & 1][wave * 2 + sp] = h;
        __syncthreads();                 // hout complete

        if (wave == 0 && lane < 16) {
            // pack 2 h -> f16x2 dword; ONE 64B-line store for the whole WG
            unsigned u0 = f2h_bits(hout[t & 1][2 * lane]);
            unsigned u1 = f2h_bits(hout[t & 1][2 * lane + 1]);
            __hip_atomic_store(hview + (size_t)t * 256 + wg * 16 + lane,
                               u0 | (u1 << 16),
                               __ATOMIC_RELAXED, __HIP_MEMORY_SCOPE_AGENT);
        }
        // no trailing barrier: hout[t&1] is next written at t+2 (other buffer
        // at t+1); reaching t+2 implies all waves passed the t+1 barrier.
    }
#undef PINU4
}

// ---- K6: logits + log_softmax (h_hist is f16) ----------------------------
__global__ void __launch_bounds__(64) out_kernel(
    const unsigned short* __restrict__ hh16, const float* __restrict__ W1T,
    const void* __restrict__ b1raw, void* __restrict__ out,
    const int* __restrict__ flagp)
{
    __shared__ float hb[512];
    int flag = flagp[0];
    int t = blockIdx.x, j = threadIdx.x;
    const unsigned* src = (const unsigned*)(hh16 + (size_t)t * 512);
#pragma unroll
    for (int kq = 0; kq < 4; ++kq) {
        unsigned u = src[j * 4 + kq];
        hb[j * 8 + 2 * kq]     = h2f_lo(u);
        hb[j * 8 + 2 * kq + 1] = h2f_hi(u);
    }
    __syncthreads();

    float acc = flag ? __bfloat162float(((const __hip_bfloat16*)b1raw)[j])
                     : ((const float*)b1raw)[j];
#pragma unroll 8
    for (int k = 0; k < 512; ++k)
        acc += hb[k] * W1T[k * 64 + j];

    float m = acc;
#pragma unroll
    for (int o = 32; o; o >>= 1) m = fmaxf(m, __shfl_xor(m, o));
    float e = __expf(acc - m);
    float s = e;
#pragma unroll
    for (int o = 32; o; o >>= 1) s += __shfl_xor(s, o);
    float r = acc - m - __logf(s);
    if (flag) ((__hip_bfloat16*)out)[t * 64 + j] = __float2bfloat16(r);
    else      ((float*)out)[t * 64 + j] = r;
}

extern "C" void kernel_launch(void* const* d_in, const int* in_sizes, int n_in,
                              void* d_out, int out_size, void* d_ws, size_t ws_size,
                              hipStream_t stream)
{
    (void)in_sizes; (void)n_in; (void)out_size; (void)ws_size;
    const void* char_emb = d_in[0];
    const void* char_Wih = d_in[1];
    const void* char_Whh = d_in[2];
    const void* char_bih = d_in[3];
    const void* char_bhh = d_in[4];
    const void* word_emb = d_in[5];
    const void* Wih      = d_in[6];
    const void* Whh      = d_in[7];
    const void* bih      = d_in[8];
    const void* bhh      = d_in[9];
    const void* W1       = d_in[10];
    const void* b1       = d_in[11];
    const int* x     = (const int*)d_in[12];
    const int* chars = (const int*)d_in[13];
    const int* lens  = (const int*)d_in[14];

    float* ws    = (float*)d_ws;
    int*   flagp = (int*)(ws + OFF_FLAG);
    float* cembf = ws + OFF_CEMB;
    float* cWihf = ws + OFF_CWIH;
    float* cbihf = ws + OFF_CBIH;
    float* cbhhf = ws + OFF_CBHH;
    float* cWhhf = ws + OFF_CWHH;
    float* bihf  = ws + OFF_BIH;
    float* bhhf  = ws + OFF_BHH;
    float* W1T   = ws + OFF_W1T;
    float* cge   = ws + OFF_CGE;
    float* charh = ws + OFF_CH;
    __hip_bfloat16* xp2 = (__hip_bfloat16*)(ws + OFF_XP2);
    unsigned short* hh16 = (unsigned short*)(ws + OFF_HH);
    unsigned short* whh16 = (unsigned short*)(ws + OFF_WHH16);

    (void)hipMemsetAsync(hh16, 0xFF, (size_t)4096 * 512 * 2, stream);

    detect_kernel<<<1, 64, 0, stream>>>((const unsigned*)char_emb, flagp);

    convf_kernel<<<(8192 + 255) / 256, 256, 0, stream>>>(char_emb, cembf, 8192, flagp);
    convf_kernel<<<(32768 + 255) / 256, 256, 0, stream>>>(char_Wih, cWihf, 32768, flagp);
    convf_kernel<<<2, 256, 0, stream>>>(char_bih, cbihf, 512, flagp);
    convf_kernel<<<2, 256, 0, stream>>>(char_bhh, cbhhf, 512, flagp);
    convf_kernel<<<(65536 + 255) / 256, 256, 0, stream>>>(char_Whh, cWhhf, 65536, flagp);
    convf_kernel<<<8, 256, 0, stream>>>(bih, bihf, 2048, flagp);
    convf_kernel<<<8, 256, 0, stream>>>(bhh, bhhf, 2048, flagp);
    w1t_kernel<<<128, 256, 0, stream>>>(W1, W1T, flagp);
    whh16_kernel<<<4096, 256, 0, stream>>>(Whh, whh16, flagp);

    cge_kernel<<<128, 256, 0, stream>>>(cembf, cWihf, cbihf, cbhhf, cge);
    char_lstm_kernel<<<256, 256, 0, stream>>>(cge, cWhhf, chars, lens, charh);
    xp2_kernel<<<256, 256, 0, stream>>>(word_emb, x, charh, Wih, bihf, bhhf, xp2, flagp);
    word_lstm_kernel<<<16, 1024, 0, stream>>>(xp2, (const unsigned*)whh16, (unsigned*)hh16);
    out_kernel<<<4096, 64, 0, stream>>>(hh16, W1T, b1, d_out, flagp);
}